// Round 1
// baseline (278.224 us; speedup 1.0000x reference)
//
#include <hip/hip_runtime.h>
#include <hip/hip_bf16.h>

#define BB 2
#define HH 16
#define SS 2048
#define DD 128
#define QBLK 64
#define KVBLK 32
#define VT_PITCH 40   // KVBLK + 8 pad -> 80B rows, 16B aligned, 2-way banks (free)
#define PP_PITCH 40

typedef __bf16 bf16x8 __attribute__((ext_vector_type(8)));
typedef float f32x4 __attribute__((ext_vector_type(4)));

__global__ __launch_bounds__(256)
void attn_fwd(const float* __restrict__ Q, const float* __restrict__ K,
              const float* __restrict__ V, const int* __restrict__ M,
              float* __restrict__ O)
{
    __shared__ __bf16 Klds[KVBLK * DD];          // XOR-swizzled rows
    __shared__ __bf16 Vt[DD * VT_PITCH];         // transposed V, padded
    __shared__ __bf16 Plds[4][16 * PP_PITCH];    // per-wave P tile

    const int tid  = threadIdx.x;
    const int w    = tid >> 6;
    const int lane = tid & 63;
    const int lr   = lane & 15;   // col within 16 / row within 16
    const int lg   = lane >> 4;   // group 0..3

    const int bh = blockIdx.y;
    const int b  = bh >> 4;                    // / H
    const int q0 = blockIdx.x * QBLK + w * 16; // this wave's first q row

    const float scale = 0.08838834764831845f;  // 1/sqrt(128)

    const float* Qb = Q + (size_t)bh * SS * DD;
    const float* Kb = K + (size_t)bh * SS * DD;
    const float* Vb = V + (size_t)bh * SS * DD;
    const int*   Mb = M + (size_t)b * SS * SS;
    float*       Ob = O + (size_t)bh * SS * DD;

    // ---- Q fragments (A-operand), once ----
    bf16x8 qf[4];
    {
        const float* qrow = Qb + (size_t)(q0 + lr) * DD;
        #pragma unroll
        for (int d0 = 0; d0 < 4; ++d0) {
            float4 f0 = *(const float4*)(qrow + d0 * 32 + lg * 8);
            float4 f1 = *(const float4*)(qrow + d0 * 32 + lg * 8 + 4);
            bf16x8 a;
            a[0] = (__bf16)f0.x; a[1] = (__bf16)f0.y; a[2] = (__bf16)f0.z; a[3] = (__bf16)f0.w;
            a[4] = (__bf16)f1.x; a[5] = (__bf16)f1.y; a[6] = (__bf16)f1.z; a[7] = (__bf16)f1.w;
            qf[d0] = a;
        }
    }

    f32x4 o[8];
    #pragma unroll
    for (int i = 0; i < 8; ++i) o[i] = (f32x4)0.0f;
    float m_i[4] = {-1e30f, -1e30f, -1e30f, -1e30f};
    float l_i[4] = {0.f, 0.f, 0.f, 0.f};

    for (int kv0 = 0; kv0 < SS; kv0 += KVBLK) {
        __syncthreads();   // previous tile fully consumed

        // ---- stage K tile: [32][128] fp32 -> bf16, XOR-swizzled 16B units ----
        {
            const int r   = tid >> 3;   // 0..31
            const int seg = tid & 7;    // 0..7, 16 floats each
            const float* src = Kb + (size_t)(kv0 + r) * DD + seg * 16;
            float4 f0 = *(const float4*)(src + 0);
            float4 f1 = *(const float4*)(src + 4);
            float4 f2 = *(const float4*)(src + 8);
            float4 f3 = *(const float4*)(src + 12);
            bf16x8 h0, h1;
            h0[0]=(__bf16)f0.x; h0[1]=(__bf16)f0.y; h0[2]=(__bf16)f0.z; h0[3]=(__bf16)f0.w;
            h0[4]=(__bf16)f1.x; h0[5]=(__bf16)f1.y; h0[6]=(__bf16)f1.z; h0[7]=(__bf16)f1.w;
            h1[0]=(__bf16)f2.x; h1[1]=(__bf16)f2.y; h1[2]=(__bf16)f2.z; h1[3]=(__bf16)f2.w;
            h1[4]=(__bf16)f3.x; h1[5]=(__bf16)f3.y; h1[6]=(__bf16)f3.z; h1[7]=(__bf16)f3.w;
            const int u0 = (seg * 2)     ^ (r & 7);
            const int u1 = (seg * 2 + 1) ^ (r & 7);
            *(bf16x8*)&Klds[r * DD + u0 * 8] = h0;
            *(bf16x8*)&Klds[r * DD + u1 * 8] = h1;
        }
        // ---- stage V tile transposed: Vt[d][k], coalesced global reads ----
        {
            const int d  = tid & 127;
            const int kh = tid >> 7;    // 0..1 -> k halves of 16
            const float* src = Vb + (size_t)(kv0 + kh * 16) * DD + d;
            bf16x8 t0, t1;
            #pragma unroll
            for (int k = 0; k < 8; ++k) t0[k] = (__bf16)src[(size_t)k * DD];
            #pragma unroll
            for (int k = 0; k < 8; ++k) t1[k] = (__bf16)src[(size_t)(k + 8) * DD];
            *(bf16x8*)&Vt[d * VT_PITCH + kh * 16]     = t0;
            *(bf16x8*)&Vt[d * VT_PITCH + kh * 16 + 8] = t1;
        }
        __syncthreads();

        // ---- QK^T: S[16][32] for this wave's 16 q rows ----
        f32x4 s[2];
        s[0] = (f32x4)0.0f; s[1] = (f32x4)0.0f;
        #pragma unroll
        for (int kt = 0; kt < 2; ++kt) {
            const int krow = kt * 16 + lr;
            #pragma unroll
            for (int d0 = 0; d0 < 4; ++d0) {
                const int u = (d0 * 4 + lg) ^ (krow & 7);
                bf16x8 bf = *(const bf16x8*)&Klds[krow * DD + u * 8];
                s[kt] = __builtin_amdgcn_mfma_f32_16x16x32_bf16(qf[d0], bf, s[kt], 0, 0, 0);
            }
        }

        // ---- mask + scale + online softmax ----
        float alpha[4];
        #pragma unroll
        for (int i = 0; i < 4; ++i) {
            const int qrow = q0 + lg * 4 + i;
            const int* mrow = Mb + (size_t)qrow * SS + kv0;
            float s0 = s[0][i] * scale - 1e9f * (float)mrow[lr];
            float s1 = s[1][i] * scale - 1e9f * (float)mrow[16 + lr];
            float mx = fmaxf(s0, s1);
            #pragma unroll
            for (int off = 8; off; off >>= 1) mx = fmaxf(mx, __shfl_xor(mx, off));
            const float newm = fmaxf(m_i[i], mx);
            const float a = __expf(m_i[i] - newm);
            m_i[i] = newm;
            alpha[i] = a;
            float p0 = __expf(s0 - newm);
            float p1 = __expf(s1 - newm);
            float rs = p0 + p1;
            #pragma unroll
            for (int off = 8; off; off >>= 1) rs += __shfl_xor(rs, off);
            l_i[i] = l_i[i] * a + rs;
            Plds[w][(lg * 4 + i) * PP_PITCH + lr]      = (__bf16)p0;
            Plds[w][(lg * 4 + i) * PP_PITCH + 16 + lr] = (__bf16)p1;
        }
        #pragma unroll
        for (int dt = 0; dt < 8; ++dt) {
            #pragma unroll
            for (int i = 0; i < 4; ++i) o[dt][i] *= alpha[i];
        }

        // ---- PV: O[16][128] += P[16][32] · V[32][128] ----
        // (intra-wave LDS RAW on Plds: compiler-inserted lgkmcnt covers it)
        bf16x8 pa = *(const bf16x8*)&Plds[w][lr * PP_PITCH + lg * 8];
        #pragma unroll
        for (int dt = 0; dt < 8; ++dt) {
            bf16x8 vb = *(const bf16x8*)&Vt[(dt * 16 + lr) * VT_PITCH + lg * 8];
            o[dt] = __builtin_amdgcn_mfma_f32_16x16x32_bf16(pa, vb, o[dt], 0, 0, 0);
        }
    }

    // ---- epilogue ----
    float inv[4];
    #pragma unroll
    for (int i = 0; i < 4; ++i) inv[i] = 1.0f / l_i[i];
    #pragma unroll
    for (int i = 0; i < 4; ++i) {
        float* orow = Ob + (size_t)(q0 + lg * 4 + i) * DD;
        #pragma unroll
        for (int dt = 0; dt < 8; ++dt)
            orow[dt * 16 + lr] = o[dt][i] * inv[i];
    }
}

extern "C" void kernel_launch(void* const* d_in, const int* in_sizes, int n_in,
                              void* d_out, int out_size, void* d_ws, size_t ws_size,
                              hipStream_t stream) {
    const float* Q = (const float*)d_in[0];
    const float* K = (const float*)d_in[1];
    const float* V = (const float*)d_in[2];
    // d_in[3] is d_k (=128), folded into the compile-time scale
    const int* M = (const int*)d_in[4];
    float* O = (float*)d_out;

    dim3 grid(SS / QBLK, BB * HH);
    dim3 block(256);
    attn_fwd<<<grid, block, 0, stream>>>(Q, K, V, M, O);
}